// Round 4
// baseline (1960.271 us; speedup 1.0000x reference)
//
#include <hip/hip_runtime.h>
#include <cstdint>

typedef unsigned short u16;
typedef unsigned int   u32;
typedef unsigned long long u64;

typedef __bf16 bf16x8 __attribute__((ext_vector_type(8)));
typedef float  f32x4  __attribute__((ext_vector_type(4)));

union U16F { uint4 u; bf16x8 f; };

__device__ __forceinline__ u16 f2bf(float f){
  union { float f; u32 i; } x; x.f = f;
  u32 u = x.i;
  u += 0x7fffu + ((u >> 16) & 1u);   // round-to-nearest-even
  return (u16)(u >> 16);
}
__device__ __forceinline__ float b2f(u16 v){
  union { u32 i; float f; } x; x.i = ((u32)v) << 16; return x.f;
}

// window-order row -> (window bw, token t) and pixel under the +3 shift map
__device__ __forceinline__ void rowmap(int row, int& gpix, int& bw_o, int& t_o){
  int bw = (int)(((u64)row * 85599ull) >> 22);   // /49, exact for row<89240
  int t  = row - bw * 49;
  int b = bw >> 4, w = bw & 15;
  int wh = w >> 2, ww = w & 3;
  int i = (t * 37) >> 8, j = t - i * 7;          // /7, exact for t<86
  int y = wh * 7 + i + 3; if (y >= 28) y -= 28;
  int x = ww * 7 + j + 3; if (x >= 28) x -= 28;
  gpix = b * 784 + y * 28 + x;
  bw_o = bw; t_o = t;
}

// ---------- weight transpose + f32->bf16: in f32 (R x C) -> out bf16 (C x R) --
__global__ __launch_bounds__(256) void transpose_wb(const float* __restrict__ in,
                                                    u16* __restrict__ out,
                                                    int R, int C){
  __shared__ float t[32][33];
  int c0 = blockIdx.x * 32, r0 = blockIdx.y * 32;
  int tx = threadIdx.x & 31, ty = threadIdx.x >> 5;
#pragma unroll
  for (int i = ty; i < 32; i += 8) t[i][tx] = in[(long)(r0 + i) * C + c0 + tx];
  __syncthreads();
#pragma unroll
  for (int i = ty; i < 32; i += 8) out[(long)(c0 + i) * R + r0 + tx] = f2bf(t[tx][i]);
}

// ---------------- fused rel-pos-bias + shift-mask table (f32) ----------------
__global__ __launch_bounds__(256) void build_tbl(const float* __restrict__ rpbt,
                                                 float* __restrict__ tbl){
  int idx = blockIdx.x * 256 + threadIdx.x;
  if (idx >= 16 * 16 * 2401) return;
  int wh16 = idx / 2401; int ij = idx - wh16 * 2401;
  int w = wh16 >> 4, h = wh16 & 15;
  int i = ij / 49, j = ij - i * 49;
  int yi = i / 7, xi = i - yi * 7;
  int yj = j / 7, xj = j - yj * 7;
  int whh = w >> 2, www = w & 3;
  int ri = ((whh == 3 && yi >= 4) ? 2 : 0) + ((www == 3 && xi >= 4) ? 1 : 0);
  int rj = ((whh == 3 && yj >= 4) ? 2 : 0) + ((www == 3 && xj >= 4) ? 1 : 0);
  float mask = (ri == rj) ? 0.f : -100.f;
  int rel = (yi - yj + 6) * 13 + (xi - xj + 6);
  tbl[idx] = rpbt[rel * 16 + h] + mask;
}

// -------- LayerNorm1 (f32 in) with shift/window gather, bf16 out (slice) -----
__global__ __launch_bounds__(256) void ln1_gather(const float* __restrict__ x,
                                                  const float* __restrict__ sc,
                                                  const float* __restrict__ bi,
                                                  u16* __restrict__ hwin, int row0){
  int rloc = blockIdx.x * 4 + (threadIdx.x >> 6);
  int lane = threadIdx.x & 63;
  int gpix, bw, t; rowmap(row0 + rloc, gpix, bw, t);
  const float* src = x + (long)gpix * 512 + lane * 8;
  float4 a = *(const float4*)src;
  float4 b = *(const float4*)(src + 4);
  float v[8] = {a.x, a.y, a.z, a.w, b.x, b.y, b.z, b.w};
  float s = 0.f, s2 = 0.f;
#pragma unroll
  for (int k = 0; k < 8; k++){ s += v[k]; s2 += v[k] * v[k]; }
#pragma unroll
  for (int m = 1; m < 64; m <<= 1){ s += __shfl_xor(s, m); s2 += __shfl_xor(s2, m); }
  float mu = s * (1.f / 512.f);
  float var = s2 * (1.f / 512.f) - mu * mu;
  float rstd = rsqrtf(var + 1e-5f);
  float4 sa = *(const float4*)(sc + lane * 8);
  float4 sb = *(const float4*)(sc + lane * 8 + 4);
  float4 ba = *(const float4*)(bi + lane * 8);
  float4 bb = *(const float4*)(bi + lane * 8 + 4);
  float svec[8] = {sa.x, sa.y, sa.z, sa.w, sb.x, sb.y, sb.z, sb.w};
  float bvec[8] = {ba.x, ba.y, ba.z, ba.w, bb.x, bb.y, bb.z, bb.w};
  u32 o[4];
#pragma unroll
  for (int k = 0; k < 4; k++){
    float a0 = (v[2*k]   - mu) * rstd * svec[2*k]   + bvec[2*k];
    float a1 = (v[2*k+1] - mu) * rstd * svec[2*k+1] + bvec[2*k+1];
    o[k] = (u32)f2bf(a0) | ((u32)f2bf(a1) << 16);
  }
  uint4 ov = {o[0], o[1], o[2], o[3]};
  *(uint4*)(hwin + (long)rloc * 512 + lane * 8) = ov;
}

// ------------- LayerNorm2: slice-local f32 in, slice-local bf16 out ---------
__global__ __launch_bounds__(256) void ln2_k(const float* __restrict__ x1,
                                             const float* __restrict__ sc,
                                             const float* __restrict__ bi,
                                             u16* __restrict__ h2){
  int row = blockIdx.x * 4 + (threadIdx.x >> 6);
  int lane = threadIdx.x & 63;
  const float* src = x1 + (long)row * 512 + lane * 8;
  float4 a = *(const float4*)(src);
  float4 b = *(const float4*)(src + 4);
  float v[8] = {a.x, a.y, a.z, a.w, b.x, b.y, b.z, b.w};
  float s = 0.f, s2 = 0.f;
#pragma unroll
  for (int k = 0; k < 8; k++){ s += v[k]; s2 += v[k] * v[k]; }
#pragma unroll
  for (int m = 1; m < 64; m <<= 1){ s += __shfl_xor(s, m); s2 += __shfl_xor(s2, m); }
  float mu = s * (1.f / 512.f);
  float var = s2 * (1.f / 512.f) - mu * mu;
  float rstd = rsqrtf(var + 1e-5f);
  float4 sa = *(const float4*)(sc + lane * 8);
  float4 sb = *(const float4*)(sc + lane * 8 + 4);
  float4 ba = *(const float4*)(bi + lane * 8);
  float4 bb = *(const float4*)(bi + lane * 8 + 4);
  float svec[8] = {sa.x, sa.y, sa.z, sa.w, sb.x, sb.y, sb.z, sb.w};
  float bvec[8] = {ba.x, ba.y, ba.z, ba.w, bb.x, bb.y, bb.z, bb.w};
  u32 o[4];
#pragma unroll
  for (int k = 0; k < 4; k++){
    float a0 = (v[2*k]   - mu) * rstd * svec[2*k]   + bvec[2*k];
    float a1 = (v[2*k+1] - mu) * rstd * svec[2*k+1] + bvec[2*k+1];
    o[k] = (u32)f2bf(a0) | ((u32)f2bf(a1) << 16);
  }
  uint4 ov = {o[0], o[1], o[2], o[3]};
  *(uint4*)(h2 + (long)row * 512 + lane * 8) = ov;
}

// ------- 128x128 bf16 GEMM, barrier-free direct-fragment loads ---------------
// Both operands are K-contiguous ([M][K] and [N][K]); the 16x16x32 A/B fragment
// (row = base+mi*16+l15, k = kt*32+quad*8) is a 16B global load. No LDS, no
// __syncthreads, no vmcnt(0) drains: the compiler software-pipelines the 8
// loads/K-step against 16 MFMAs with counted waits. L2 feeds reuse (A slab
// shared across the tn sweep; B fully L2-resident).
// MODE 0: qkv  -> qs slice-local (row,1536) bf16, Q cols pre-scaled
// MODE 1: proj -> x1s(f32, slice-local) = out + gather(x f32 at global row)
// MODE 2: fc1  -> hidden(slice-local bf16) = gelu_tanh(out)
// MODE 3: fc2  -> d_out(f32) = out + x1s(local), scattered to pixel order
template<int MODE, int KDIM>
__global__ __launch_bounds__(256) void gemm_k(
    const u16* __restrict__ A, const u16* __restrict__ Bt,
    const float* __restrict__ bias,
    u16* __restrict__ o1, float* __restrict__ of,
    const float* __restrict__ xg, const float* __restrict__ x1r,
    int ntn, int erow0)
{
  const int tid = threadIdx.x;
  const int wave = tid >> 6, lane = tid & 63;
  const int quad = lane >> 4, l15 = lane & 15;
  const int tn = blockIdx.x % ntn, tm = blockIdx.x / ntn;
  const int wy = wave >> 1, wx = wave & 1;

  // per-lane fragment base pointers (16B-aligned; rows are 16B-multiples apart)
  const u16* ap = A  + (size_t)(tm * 128 + wy * 64 + l15) * KDIM + quad * 8;
  const u16* bp = Bt + (size_t)(tn * 128 + wx * 64 + l15) * KDIM + quad * 8;

  f32x4 acc[4][4];
#pragma unroll
  for (int i = 0; i < 4; i++)
#pragma unroll
    for (int j = 0; j < 4; j++) acc[i][j] = (f32x4){0.f, 0.f, 0.f, 0.f};

#pragma unroll 4
  for (int kt = 0; kt < KDIM / 32; ++kt){
    U16F af[4], bf[4];
#pragma unroll
    for (int mi = 0; mi < 4; mi++)
      af[mi].u = *(const uint4*)(ap + (size_t)mi * 16 * KDIM + kt * 32);
#pragma unroll
    for (int ni = 0; ni < 4; ni++)
      bf[ni].u = *(const uint4*)(bp + (size_t)ni * 16 * KDIM + kt * 32);
#pragma unroll
    for (int mi = 0; mi < 4; mi++)
#pragma unroll
      for (int ni = 0; ni < 4; ni++)
        acc[mi][ni] = __builtin_amdgcn_mfma_f32_16x16x32_bf16(af[mi].f, bf[ni].f, acc[mi][ni], 0, 0, 0);
  }

  // ---- epilogue ----
  const int colbase = tn * 128 + wx * 64;
  float bv[4];
#pragma unroll
  for (int ni = 0; ni < 4; ni++) bv[ni] = bias[colbase + ni * 16 + l15];
  const int rowbase = tm * 128 + wy * 64;

#pragma unroll
  for (int mi = 0; mi < 4; mi++){
#pragma unroll
    for (int r = 0; r < 4; r++){
      int rloc = rowbase + mi * 16 + quad * 4 + r;   // slice-local row
      int row = erow0 + rloc;                        // global window-order row
      if constexpr (MODE == 0){
        long obase = (long)rloc * 1536;
#pragma unroll
        for (int ni = 0; ni < 4; ni++){
          int col = colbase + ni * 16 + l15;
          float v = acc[mi][ni][r] + bv[ni];
          if (col < 512) v *= 0.17677669529663689f;   // q scale = 1/sqrt(32)
          o1[obase + col] = f2bf(v);
        }
      } else if constexpr (MODE == 1){
        int gpix, bw, t; rowmap(row, gpix, bw, t);
        long gbase = (long)gpix * 512;
        long obase = (long)rloc * 512;
#pragma unroll
        for (int ni = 0; ni < 4; ni++){
          int col = colbase + ni * 16 + l15;
          of[obase + col] = acc[mi][ni][r] + bv[ni] + xg[gbase + col];
        }
      } else if constexpr (MODE == 2){
        long obase = (long)rloc * 2048;
#pragma unroll
        for (int ni = 0; ni < 4; ni++){
          int col = colbase + ni * 16 + l15;
          float v = acc[mi][ni][r] + bv[ni];
          float z = 0.7978845608f * (v + 0.044715f * v * v * v);
          float th = 1.f - 2.f / (__expf(2.f * z) + 1.f);
          o1[obase + col] = f2bf(0.5f * v * (1.f + th));
        }
      } else {
        int gpix, bw, t; rowmap(row, gpix, bw, t);
        long gbase = (long)gpix * 512;
        long rbase = (long)rloc * 512;
#pragma unroll
        for (int ni = 0; ni < 4; ni++){
          int col = colbase + ni * 16 + l15;
          of[gbase + col] = acc[mi][ni][r] + bv[ni] + x1r[rbase + col];
        }
      }
    }
  }
}

// ---------------- windowed attention: one wave per (window, head) ----------
// qkv slice-local (row,1536) bf16; writes slice-local aout rows (bw*49+t).
__global__ __launch_bounds__(64) void attn_k(const u16* __restrict__ qkv,
                                             const float* __restrict__ tbl,
                                             u16* __restrict__ aout){
  __shared__ u16 P[64 * 72];
  __shared__ u16 Vt[32 * 72];
  const int blk = blockIdx.x;            // bw_local*16 + h
  const int bw = blk >> 4, h = blk & 15;
  const int lane = threadIdx.x & 63;
  const int quad = lane >> 4, l15 = lane & 15;
  const long rb = (long)(bw * 49) * 1536;
  const int hoff = h * 32;

  uint4 vraw[4];
#pragma unroll
  for (int p = 0; p < 4; p++){
    int t = p * 16 + (lane >> 2);
    int d0 = (lane & 3) * 8;
    vraw[p] = *(const uint4*)(qkv + rb + (long)t * 1536 + 1024 + hoff + d0);
  }

  U16F qf[4], kf[4];
#pragma unroll
  for (int mi = 0; mi < 4; mi++)
    qf[mi].u = *(const uint4*)(qkv + rb + (long)(mi * 16 + l15) * 1536 + hoff + quad * 8);
#pragma unroll
  for (int ni = 0; ni < 4; ni++)
    kf[ni].u = *(const uint4*)(qkv + rb + (long)(ni * 16 + l15) * 1536 + 512 + hoff + quad * 8);
  f32x4 S[4][4];
#pragma unroll
  for (int i = 0; i < 4; i++)
#pragma unroll
    for (int j = 0; j < 4; j++) S[i][j] = (f32x4){0.f, 0.f, 0.f, 0.f};
#pragma unroll
  for (int mi = 0; mi < 4; mi++)
#pragma unroll
    for (int ni = 0; ni < 4; ni++)
      S[mi][ni] = __builtin_amdgcn_mfma_f32_16x16x32_bf16(qf[mi].f, kf[ni].f, S[mi][ni], 0, 0, 0);

#pragma unroll
  for (int p = 0; p < 4; p++){
    int t = p * 16 + (lane >> 2);
    int d0 = (lane & 3) * 8;
    u32 wv[4] = {vraw[p].x, vraw[p].y, vraw[p].z, vraw[p].w};
#pragma unroll
    for (int k = 0; k < 4; k++){
      Vt[(d0 + 2 * k)     * 72 + t] = (u16)(wv[k] & 0xffff);
      Vt[(d0 + 2 * k + 1) * 72 + t] = (u16)(wv[k] >> 16);
    }
  }

  const int w = bw & 15;   // windows/slice multiple of 16: local == global mod 16
  const float* t0 = tbl + (long)(w * 16 + h) * 2401;
#pragma unroll
  for (int mi = 0; mi < 4; mi++){
#pragma unroll
    for (int r = 0; r < 4; r++){
      int row = mi * 16 + quad * 4 + r;
      float sv[4];
#pragma unroll
      for (int ni = 0; ni < 4; ni++){
        int col = ni * 16 + l15;
        float s;
        if (col < 49){
          s = S[mi][ni][r];
          if (row < 49) s += t0[row * 49 + col];
        } else s = -1e30f;
        sv[ni] = s;
      }
      float mx = fmaxf(fmaxf(sv[0], sv[1]), fmaxf(sv[2], sv[3]));
#pragma unroll
      for (int m = 1; m < 16; m <<= 1) mx = fmaxf(mx, __shfl_xor(mx, m));
      float e[4], sum = 0.f;
#pragma unroll
      for (int ni = 0; ni < 4; ni++){ e[ni] = __expf(sv[ni] - mx); sum += e[ni]; }
#pragma unroll
      for (int m = 1; m < 16; m <<= 1) sum += __shfl_xor(sum, m);
      float inv = 1.f / sum;
#pragma unroll
      for (int ni = 0; ni < 4; ni++)
        P[row * 72 + ni * 16 + l15] = f2bf(e[ni] * inv);
    }
  }
  __syncthreads();

  U16F vf[2][2];
#pragma unroll
  for (int ks = 0; ks < 2; ks++)
#pragma unroll
    for (int nj = 0; nj < 2; nj++)
      vf[ks][nj].u = *(const uint4*)&Vt[(nj * 16 + l15) * 72 + ks * 32 + quad * 8];
  f32x4 O[4][2];
#pragma unroll
  for (int i = 0; i < 4; i++)
#pragma unroll
    for (int j = 0; j < 2; j++) O[i][j] = (f32x4){0.f, 0.f, 0.f, 0.f};
#pragma unroll
  for (int ks = 0; ks < 2; ks++){
#pragma unroll
    for (int mi = 0; mi < 4; mi++){
      U16F pf;
      pf.u = *(const uint4*)&P[(mi * 16 + l15) * 72 + ks * 32 + quad * 8];
#pragma unroll
      for (int nj = 0; nj < 2; nj++)
        O[mi][nj] = __builtin_amdgcn_mfma_f32_16x16x32_bf16(pf.f, vf[ks][nj].f, O[mi][nj], 0, 0, 0);
    }
  }
#pragma unroll
  for (int mi = 0; mi < 4; mi++){
#pragma unroll
    for (int r = 0; r < 4; r++){
      int t = mi * 16 + quad * 4 + r;
      if (t < 49){
        long ob = ((long)(bw * 49 + t)) * 512 + hoff;
#pragma unroll
        for (int nj = 0; nj < 2; nj++)
          aout[ob + nj * 16 + l15] = f2bf(O[mi][nj][r]);
      }
    }
  }
}

// ---------------- launch ----------------
extern "C" void kernel_launch(void* const* d_in, const int* in_sizes, int n_in,
                              void* d_out, int out_size, void* d_ws, size_t ws_size,
                              hipStream_t stream)
{
  (void)in_sizes; (void)n_in; (void)out_size; (void)ws_size;
  const float* x      = (const float*)d_in[0];
  const float* qkv_w  = (const float*)d_in[1];
  const float* qkv_b  = (const float*)d_in[2];
  const float* proj_w = (const float*)d_in[3];
  const float* proj_b = (const float*)d_in[4];
  const float* rpbt   = (const float*)d_in[5];
  const float* n1s    = (const float*)d_in[6];
  const float* n1b    = (const float*)d_in[7];
  const float* n2s    = (const float*)d_in[8];
  const float* n2b    = (const float*)d_in[9];
  const float* fc1_w  = (const float*)d_in[10];
  const float* fc1_b  = (const float*)d_in[11];
  const float* fc2_w  = (const float*)d_in[12];
  const float* fc2_b  = (const float*)d_in[13];
  float* out = (float*)d_out;

  // ---- workspace plan: ~99 MB peak ----
  const int NS = 4;                 // slices
  const int RS = 50176 / NS;        // 12544 rows = 98 tiles = 256 windows
  char* ws = (char*)d_ws;
  size_t off = 0;
  auto alloc = [&](size_t bytes) -> char* {
    char* p = ws + off;
    off = (off + bytes + 255) & ~(size_t)255;
    return p;
  };
  float* tbl  = (float*)alloc((size_t)614656 * 4);
  u16*  wtq   = (u16*)alloc((size_t)1536 * 512 * 2);
  u16*  wtp   = (u16*)alloc((size_t)512 * 512 * 2);
  u16*  wtf1  = (u16*)alloc((size_t)2048 * 512 * 2);
  u16*  wtf2  = (u16*)alloc((size_t)512 * 2048 * 2);
  u16*  Cs    = (u16*)alloc((size_t)RS * 512 * 2);        // ln1 -> attnout -> h2
  char* Breg  = alloc((size_t)RS * 6144);                 // qs | x1s+hidden
  u16*  qs    = (u16*)Breg;                               // RS x 1536 bf16
  float* x1s  = (float*)Breg;                             // RS x 512 f32
  u16*  hidden= (u16*)(Breg + (size_t)RS * 2048);         // RS x 2048 bf16

  transpose_wb<<<dim3(1536/32, 512/32), 256, 0, stream>>>(qkv_w, wtq, 512, 1536);
  transpose_wb<<<dim3(512/32, 512/32), 256, 0, stream>>>(proj_w, wtp, 512, 512);
  transpose_wb<<<dim3(2048/32, 512/32), 256, 0, stream>>>(fc1_w, wtf1, 512, 2048);
  transpose_wb<<<dim3(512/32, 2048/32), 256, 0, stream>>>(fc2_w, wtf2, 2048, 512);
  build_tbl<<<2401, 256, 0, stream>>>(rpbt, tbl);

  for (int s = 0; s < NS; s++){
    ln1_gather<<<RS/4, 256, 0, stream>>>(x, n1s, n1b, Cs, s * RS);
    gemm_k<0, 512><<<(RS/128) * 12, 256, 0, stream>>>(Cs, wtq, qkv_b, qs, nullptr,
                                                      nullptr, nullptr, 12, 0);
    attn_k<<<(RS/49) * 16, 64, 0, stream>>>(qs, tbl, Cs);
    gemm_k<1, 512><<<(RS/128) * 4, 256, 0, stream>>>(Cs, wtp, proj_b, nullptr, x1s,
                                                     x, nullptr, 4, s * RS);
    ln2_k<<<RS/4, 256, 0, stream>>>(x1s, n2s, n2b, Cs);
    gemm_k<2, 512><<<(RS/128) * 16, 256, 0, stream>>>(Cs, wtf1, fc1_b, hidden, nullptr,
                                                      nullptr, nullptr, 16, 0);
    gemm_k<3, 2048><<<(RS/128) * 4, 256, 0, stream>>>(hidden, wtf2, fc2_b, nullptr, out,
                                                      nullptr, x1s, 4, s * RS);
  }
}

// Round 6
// 886.818 us; speedup vs baseline: 2.2105x; 2.2105x over previous
//
#include <hip/hip_runtime.h>
#include <cstdint>

typedef unsigned short u16;
typedef unsigned int   u32;
typedef unsigned long long u64;

typedef __bf16 bf16x8 __attribute__((ext_vector_type(8)));
typedef float  f32x4  __attribute__((ext_vector_type(4)));

union U16F { uint4 u; bf16x8 f; };

__device__ __forceinline__ u16 f2bf(float f){
  union { float f; u32 i; } x; x.f = f;
  u32 u = x.i;
  u += 0x7fffu + ((u >> 16) & 1u);   // round-to-nearest-even
  return (u16)(u >> 16);
}
__device__ __forceinline__ float b2f(u16 v){
  union { u32 i; float f; } x; x.i = ((u32)v) << 16; return x.f;
}

// async global->LDS DMA, 16B per lane. LDS dest is wave-uniform base + lane*16;
// global src is per-lane. (guide §5: compiler never auto-emits this.)
typedef __attribute__((address_space(1))) const u32 GAS_u32;
typedef __attribute__((address_space(3))) u32 LAS_u32;
__device__ __forceinline__ void gll16(const u16* g, u16* l){
  __builtin_amdgcn_global_load_lds((GAS_u32*)g, (LAS_u32*)l, 16, 0, 0);
}

// window-order row -> (window bw, token t) and pixel under the +3 shift map
__device__ __forceinline__ void rowmap(int row, int& gpix, int& bw_o, int& t_o){
  int bw = (int)(((u64)row * 85599ull) >> 22);   // /49, exact for row<89240
  int t  = row - bw * 49;
  int b = bw >> 4, w = bw & 15;
  int wh = w >> 2, ww = w & 3;
  int i = (t * 37) >> 8, j = t - i * 7;          // /7, exact for t<86
  int y = wh * 7 + i + 3; if (y >= 28) y -= 28;
  int x = ww * 7 + j + 3; if (x >= 28) x -= 28;
  gpix = b * 784 + y * 28 + x;
  bw_o = bw; t_o = t;
}

// ---------- weight transpose + f32->bf16: in f32 (R x C) -> out bf16 (C x R) --
__global__ __launch_bounds__(256) void transpose_wb(const float* __restrict__ in,
                                                    u16* __restrict__ out,
                                                    int R, int C){
  __shared__ float t[32][33];
  int c0 = blockIdx.x * 32, r0 = blockIdx.y * 32;
  int tx = threadIdx.x & 31, ty = threadIdx.x >> 5;
#pragma unroll
  for (int i = ty; i < 32; i += 8) t[i][tx] = in[(long)(r0 + i) * C + c0 + tx];
  __syncthreads();
#pragma unroll
  for (int i = ty; i < 32; i += 8) out[(long)(c0 + i) * R + r0 + tx] = f2bf(t[tx][i]);
}

// ---------------- fused rel-pos-bias + shift-mask table (f32) ----------------
__global__ __launch_bounds__(256) void build_tbl(const float* __restrict__ rpbt,
                                                 float* __restrict__ tbl){
  int idx = blockIdx.x * 256 + threadIdx.x;
  if (idx >= 16 * 16 * 2401) return;
  int wh16 = idx / 2401; int ij = idx - wh16 * 2401;
  int w = wh16 >> 4, h = wh16 & 15;
  int i = ij / 49, j = ij - i * 49;
  int yi = i / 7, xi = i - yi * 7;
  int yj = j / 7, xj = j - yj * 7;
  int whh = w >> 2, www = w & 3;
  int ri = ((whh == 3 && yi >= 4) ? 2 : 0) + ((www == 3 && xi >= 4) ? 1 : 0);
  int rj = ((whh == 3 && yj >= 4) ? 2 : 0) + ((www == 3 && xj >= 4) ? 1 : 0);
  float mask = (ri == rj) ? 0.f : -100.f;
  int rel = (yi - yj + 6) * 13 + (xi - xj + 6);
  tbl[idx] = rpbt[rel * 16 + h] + mask;
}

// -------- LayerNorm1 (f32 in) with shift/window gather, bf16 out (slice) -----
__global__ __launch_bounds__(256) void ln1_gather(const float* __restrict__ x,
                                                  const float* __restrict__ sc,
                                                  const float* __restrict__ bi,
                                                  u16* __restrict__ hwin, int row0){
  int rloc = blockIdx.x * 4 + (threadIdx.x >> 6);
  int lane = threadIdx.x & 63;
  int gpix, bw, t; rowmap(row0 + rloc, gpix, bw, t);
  const float* src = x + (long)gpix * 512 + lane * 8;
  float4 a = *(const float4*)src;
  float4 b = *(const float4*)(src + 4);
  float v[8] = {a.x, a.y, a.z, a.w, b.x, b.y, b.z, b.w};
  float s = 0.f, s2 = 0.f;
#pragma unroll
  for (int k = 0; k < 8; k++){ s += v[k]; s2 += v[k] * v[k]; }
#pragma unroll
  for (int m = 1; m < 64; m <<= 1){ s += __shfl_xor(s, m); s2 += __shfl_xor(s2, m); }
  float mu = s * (1.f / 512.f);
  float var = s2 * (1.f / 512.f) - mu * mu;
  float rstd = rsqrtf(var + 1e-5f);
  float4 sa = *(const float4*)(sc + lane * 8);
  float4 sb = *(const float4*)(sc + lane * 8 + 4);
  float4 ba = *(const float4*)(bi + lane * 8);
  float4 bb = *(const float4*)(bi + lane * 8 + 4);
  float svec[8] = {sa.x, sa.y, sa.z, sa.w, sb.x, sb.y, sb.z, sb.w};
  float bvec[8] = {ba.x, ba.y, ba.z, ba.w, bb.x, bb.y, bb.z, bb.w};
  u32 o[4];
#pragma unroll
  for (int k = 0; k < 4; k++){
    float a0 = (v[2*k]   - mu) * rstd * svec[2*k]   + bvec[2*k];
    float a1 = (v[2*k+1] - mu) * rstd * svec[2*k+1] + bvec[2*k+1];
    o[k] = (u32)f2bf(a0) | ((u32)f2bf(a1) << 16);
  }
  uint4 ov = {o[0], o[1], o[2], o[3]};
  *(uint4*)(hwin + (long)rloc * 512 + lane * 8) = ov;
}

// ------------- LayerNorm2: slice-local f32 in, slice-local bf16 out ---------
__global__ __launch_bounds__(256) void ln2_k(const float* __restrict__ x1,
                                             const float* __restrict__ sc,
                                             const float* __restrict__ bi,
                                             u16* __restrict__ h2){
  int row = blockIdx.x * 4 + (threadIdx.x >> 6);
  int lane = threadIdx.x & 63;
  const float* src = x1 + (long)row * 512 + lane * 8;
  float4 a = *(const float4*)(src);
  float4 b = *(const float4*)(src + 4);
  float v[8] = {a.x, a.y, a.z, a.w, b.x, b.y, b.z, b.w};
  float s = 0.f, s2 = 0.f;
#pragma unroll
  for (int k = 0; k < 8; k++){ s += v[k]; s2 += v[k] * v[k]; }
#pragma unroll
  for (int m = 1; m < 64; m <<= 1){ s += __shfl_xor(s, m); s2 += __shfl_xor(s2, m); }
  float mu = s * (1.f / 512.f);
  float var = s2 * (1.f / 512.f) - mu * mu;
  float rstd = rsqrtf(var + 1e-5f);
  float4 sa = *(const float4*)(sc + lane * 8);
  float4 sb = *(const float4*)(sc + lane * 8 + 4);
  float4 ba = *(const float4*)(bi + lane * 8);
  float4 bb = *(const float4*)(bi + lane * 8 + 4);
  float svec[8] = {sa.x, sa.y, sa.z, sa.w, sb.x, sb.y, sb.z, sb.w};
  float bvec[8] = {ba.x, ba.y, ba.z, ba.w, bb.x, bb.y, bb.z, bb.w};
  u32 o[4];
#pragma unroll
  for (int k = 0; k < 4; k++){
    float a0 = (v[2*k]   - mu) * rstd * svec[2*k]   + bvec[2*k];
    float a1 = (v[2*k+1] - mu) * rstd * svec[2*k+1] + bvec[2*k+1];
    o[k] = (u32)f2bf(a0) | ((u32)f2bf(a1) << 16);
  }
  uint4 ov = {o[0], o[1], o[2], o[3]};
  *(uint4*)(h2 + (long)row * 512 + lane * 8) = ov;
}

// ------- 128x128 bf16 GEMM, global_load_lds direct staging (round-1 form) ----
// K-loop: issue 4x global_load_lds_dwordx4 -> barrier (vmcnt(0) drain) ->
// ds_read frags -> 16x MFMA -> barrier. Verified 999us anchor.
// MODE 0: qkv  -> qs slice-local (row,1536) bf16, Q cols pre-scaled
// MODE 1: proj -> x1s(f32, slice-local) = out + gather(x f32 at global row)
// MODE 2: fc1  -> hidden(slice-local bf16) = gelu(out) = v*sigmoid(2z)
// MODE 3: fc2  -> d_out(f32) = out + x1s(local), scattered to pixel order
template<int MODE, int KDIM>
__global__ __launch_bounds__(256) void gemm_k(
    const u16* __restrict__ A, const u16* __restrict__ Bt,
    const float* __restrict__ bias,
    u16* __restrict__ o1, float* __restrict__ of,
    const float* __restrict__ xg, const float* __restrict__ x1r,
    int ntn, int erow0)
{
  __shared__ u16 Alds[128 * 32];
  __shared__ u16 Blds[128 * 32];
  const int tid = threadIdx.x;
  const int wave = tid >> 6, lane = tid & 63;
  const int quad = lane >> 4, l15 = lane & 15;
  const int tn = blockIdx.x % ntn, tm = blockIdx.x / ntn;
  const int wy = wave >> 1, wx = wave & 1;

  // staging: lane l of wave w covers LDS rows {w*16 + (l>>2), +64}, 8-elem chunk (l&3)
  const u16* agp = A  + (size_t)(tm * 128 + wave * 16 + (lane >> 2)) * KDIM + (lane & 3) * 8;
  const u16* bgp = Bt + (size_t)(tn * 128 + wave * 16 + (lane >> 2)) * KDIM + (lane & 3) * 8;
  u16* alb = &Alds[wave * 512];   // + lane*16B implicit in the DMA
  u16* blb = &Blds[wave * 512];

  f32x4 acc[4][4];
#pragma unroll
  for (int i = 0; i < 4; i++)
#pragma unroll
    for (int j = 0; j < 4; j++) acc[i][j] = (f32x4){0.f, 0.f, 0.f, 0.f};

  for (int kt = 0; kt < KDIM / 32; ++kt){
    const u16* a0 = agp + kt * 32;
    const u16* b0 = bgp + kt * 32;
    gll16(a0, alb);
    gll16(a0 + (size_t)64 * KDIM, alb + 2048);
    gll16(b0, blb);
    gll16(b0 + (size_t)64 * KDIM, blb + 2048);
    __syncthreads();                       // vmcnt(0): DMA landed, all waves here
    U16F af[4], bf[4];
#pragma unroll
    for (int mi = 0; mi < 4; mi++)
      af[mi].u = *(const uint4*)&Alds[(wy * 64 + mi * 16 + l15) * 32 + quad * 8];
#pragma unroll
    for (int ni = 0; ni < 4; ni++)
      bf[ni].u = *(const uint4*)&Blds[(wx * 64 + ni * 16 + l15) * 32 + quad * 8];
#pragma unroll
    for (int mi = 0; mi < 4; mi++)
#pragma unroll
      for (int ni = 0; ni < 4; ni++)
        acc[mi][ni] = __builtin_amdgcn_mfma_f32_16x16x32_bf16(af[mi].f, bf[ni].f, acc[mi][ni], 0, 0, 0);
    __syncthreads();                       // protect LDS from next iter's DMA
  }

  // ---- epilogue ----
  const int colbase = tn * 128 + wx * 64;
  float bv[4];
#pragma unroll
  for (int ni = 0; ni < 4; ni++) bv[ni] = bias[colbase + ni * 16 + l15];
  const int rowbase = tm * 128 + wy * 64;

#pragma unroll
  for (int mi = 0; mi < 4; mi++){
#pragma unroll
    for (int r = 0; r < 4; r++){
      int rloc = rowbase + mi * 16 + quad * 4 + r;   // slice-local row
      int row = erow0 + rloc;                        // global window-order row
      if constexpr (MODE == 0){
        long obase = (long)rloc * 1536;
#pragma unroll
        for (int ni = 0; ni < 4; ni++){
          int col = colbase + ni * 16 + l15;
          float v = acc[mi][ni][r] + bv[ni];
          if (col < 512) v *= 0.17677669529663689f;   // q scale = 1/sqrt(32)
          o1[obase + col] = f2bf(v);
        }
      } else if constexpr (MODE == 1){
        int gpix, bw, t; rowmap(row, gpix, bw, t);
        long gbase = (long)gpix * 512;
        long obase = (long)rloc * 512;
#pragma unroll
        for (int ni = 0; ni < 4; ni++){
          int col = colbase + ni * 16 + l15;
          of[obase + col] = acc[mi][ni][r] + bv[ni] + xg[gbase + col];
        }
      } else if constexpr (MODE == 2){
        long obase = (long)rloc * 2048;
#pragma unroll
        for (int ni = 0; ni < 4; ni++){
          int col = colbase + ni * 16 + l15;
          float v = acc[mi][ni][r] + bv[ni];
          // gelu_tanh(v) == v*sigmoid(2z), 2z = v*(1.5957691 + 0.07135481 v^2)
          float zz = v * (1.5957691216f + 0.0713548135f * v * v);
          float sg = 1.f / (1.f + __expf(-zz));
          o1[obase + col] = f2bf(v * sg);
        }
      } else {
        int gpix, bw, t; rowmap(row, gpix, bw, t);
        long gbase = (long)gpix * 512;
        long rbase = (long)rloc * 512;
#pragma unroll
        for (int ni = 0; ni < 4; ni++){
          int col = colbase + ni * 16 + l15;
          of[gbase + col] = acc[mi][ni][r] + bv[ni] + x1r[rbase + col];
        }
      }
    }
  }
}

// ---------------- windowed attention: one wave per (window, head) ----------
// qkv slice-local (row,1536) bf16; writes slice-local aout rows (bw*49+t).
__global__ __launch_bounds__(64) void attn_k(const u16* __restrict__ qkv,
                                             const float* __restrict__ tbl,
                                             u16* __restrict__ aout){
  __shared__ u16 P[64 * 72];
  __shared__ u16 Vt[32 * 72];
  const int blk = blockIdx.x;            // bw_local*16 + h
  const int bw = blk >> 4, h = blk & 15;
  const int lane = threadIdx.x & 63;
  const int quad = lane >> 4, l15 = lane & 15;
  const long rb = (long)(bw * 49) * 1536;
  const int hoff = h * 32;

  uint4 vraw[4];
#pragma unroll
  for (int p = 0; p < 4; p++){
    int t = p * 16 + (lane >> 2);
    int d0 = (lane & 3) * 8;
    vraw[p] = *(const uint4*)(qkv + rb + (long)t * 1536 + 1024 + hoff + d0);
  }

  U16F qf[4], kf[4];
#pragma unroll
  for (int mi = 0; mi < 4; mi++)
    qf[mi].u = *(const uint4*)(qkv + rb + (long)(mi * 16 + l15) * 1536 + hoff + quad * 8);
#pragma unroll
  for (int ni = 0; ni < 4; ni++)
    kf[ni].u = *(const uint4*)(qkv + rb + (long)(ni * 16 + l15) * 1536 + 512 + hoff + quad * 8);
  f32x4 S[4][4];
#pragma unroll
  for (int i = 0; i < 4; i++)
#pragma unroll
    for (int j = 0; j < 4; j++) S[i][j] = (f32x4){0.f, 0.f, 0.f, 0.f};
#pragma unroll
  for (int mi = 0; mi < 4; mi++)
#pragma unroll
    for (int ni = 0; ni < 4; ni++)
      S[mi][ni] = __builtin_amdgcn_mfma_f32_16x16x32_bf16(qf[mi].f, kf[ni].f, S[mi][ni], 0, 0, 0);

#pragma unroll
  for (int p = 0; p < 4; p++){
    int t = p * 16 + (lane >> 2);
    int d0 = (lane & 3) * 8;
    u32 wv[4] = {vraw[p].x, vraw[p].y, vraw[p].z, vraw[p].w};
#pragma unroll
    for (int k = 0; k < 4; k++){
      Vt[(d0 + 2 * k)     * 72 + t] = (u16)(wv[k] & 0xffff);
      Vt[(d0 + 2 * k + 1) * 72 + t] = (u16)(wv[k] >> 16);
    }
  }

  const int w = bw & 15;   // windows/slice multiple of 16: local == global mod 16
  const float* t0 = tbl + (long)(w * 16 + h) * 2401;
#pragma unroll
  for (int mi = 0; mi < 4; mi++){
#pragma unroll
    for (int r = 0; r < 4; r++){
      int row = mi * 16 + quad * 4 + r;
      float sv[4];
#pragma unroll
      for (int ni = 0; ni < 4; ni++){
        int col = ni * 16 + l15;
        float s;
        if (col < 49){
          s = S[mi][ni][r];
          if (row < 49) s += t0[row * 49 + col];
        } else s = -1e30f;
        sv[ni] = s;
      }
      float mx = fmaxf(fmaxf(sv[0], sv[1]), fmaxf(sv[2], sv[3]));
#pragma unroll
      for (int m = 1; m < 16; m <<= 1) mx = fmaxf(mx, __shfl_xor(mx, m));
      float e[4], sum = 0.f;
#pragma unroll
      for (int ni = 0; ni < 4; ni++){ e[ni] = __expf(sv[ni] - mx); sum += e[ni]; }
#pragma unroll
      for (int m = 1; m < 16; m <<= 1) sum += __shfl_xor(sum, m);
      float inv = 1.f / sum;
#pragma unroll
      for (int ni = 0; ni < 4; ni++)
        P[row * 72 + ni * 16 + l15] = f2bf(e[ni] * inv);
    }
  }
  __syncthreads();

  U16F vf[2][2];
#pragma unroll
  for (int ks = 0; ks < 2; ks++)
#pragma unroll
    for (int nj = 0; nj < 2; nj++)
      vf[ks][nj].u = *(const uint4*)&Vt[(nj * 16 + l15) * 72 + ks * 32 + quad * 8];
  f32x4 O[4][2];
#pragma unroll
  for (int i = 0; i < 4; i++)
#pragma unroll
    for (int j = 0; j < 2; j++) O[i][j] = (f32x4){0.f, 0.f, 0.f, 0.f};
#pragma unroll
  for (int ks = 0; ks < 2; ks++){
#pragma unroll
    for (int mi = 0; mi < 4; mi++){
      U16F pf;
      pf.u = *(const uint4*)&P[(mi * 16 + l15) * 72 + ks * 32 + quad * 8];
#pragma unroll
      for (int nj = 0; nj < 2; nj++)
        O[mi][nj] = __builtin_amdgcn_mfma_f32_16x16x32_bf16(pf.f, vf[ks][nj].f, O[mi][nj], 0, 0, 0);
    }
  }
#pragma unroll
  for (int mi = 0; mi < 4; mi++){
#pragma unroll
    for (int r = 0; r < 4; r++){
      int t = mi * 16 + quad * 4 + r;
      if (t < 49){
        long ob = ((long)(bw * 49 + t)) * 512 + hoff;
#pragma unroll
        for (int nj = 0; nj < 2; nj++)
          aout[ob + nj * 16 + l15] = f2bf(O[mi][nj][r]);
      }
    }
  }
}

// ---------------- launch ----------------
extern "C" void kernel_launch(void* const* d_in, const int* in_sizes, int n_in,
                              void* d_out, int out_size, void* d_ws, size_t ws_size,
                              hipStream_t stream)
{
  (void)in_sizes; (void)n_in; (void)out_size;
  const float* x      = (const float*)d_in[0];
  const float* qkv_w  = (const float*)d_in[1];
  const float* qkv_b  = (const float*)d_in[2];
  const float* proj_w = (const float*)d_in[3];
  const float* proj_b = (const float*)d_in[4];
  const float* rpbt   = (const float*)d_in[5];
  const float* n1s    = (const float*)d_in[6];
  const float* n1b    = (const float*)d_in[7];
  const float* n2s    = (const float*)d_in[8];
  const float* n2b    = (const float*)d_in[9];
  const float* fc1_w  = (const float*)d_in[10];
  const float* fc1_b  = (const float*)d_in[11];
  const float* fc2_w  = (const float*)d_in[12];
  const float* fc2_b  = (const float*)d_in[13];
  float* out = (float*)d_out;

  // ---- workspace plan: NS slices; prefer NS=1 (one big grid per GEMM class,
  // 392-block tails become 1568-block grids), fall back if ws too small ----
  const size_t FIXED = ((size_t)614656 * 4 + 256) + ((size_t)1536 * 512 * 2 + 256) +
                       ((size_t)512 * 512 * 2 + 256) + ((size_t)2048 * 512 * 2 + 256) +
                       ((size_t)512 * 2048 * 2 + 256);
  int NS = 1;
  for (; NS <= 4; NS *= 2){
    size_t rs = 50176 / NS;
    size_t need = FIXED + (rs * 1024 + 256) + rs * 6144 + 1024;
    if (need <= ws_size) break;
  }
  if (NS > 4) NS = 4;
  const int RS = 50176 / NS;        // rows per slice (multiple of 128 and 784)

  char* ws = (char*)d_ws;
  size_t off = 0;
  auto alloc = [&](size_t bytes) -> char* {
    char* p = ws + off;
    off = (off + bytes + 255) & ~(size_t)255;
    return p;
  };
  float* tbl  = (float*)alloc((size_t)614656 * 4);
  u16*  wtq   = (u16*)alloc((size_t)1536 * 512 * 2);
  u16*  wtp   = (u16*)alloc((size_t)512 * 512 * 2);
  u16*  wtf1  = (u16*)alloc((size_t)2048 * 512 * 2);
  u16*  wtf2  = (u16*)alloc((size_t)512 * 2048 * 2);
  u16*  Cs    = (u16*)alloc((size_t)RS * 512 * 2);        // ln1 -> attnout -> h2
  char* Breg  = alloc((size_t)RS * 6144);                 // qs | x1s+hidden
  u16*  qs    = (u16*)Breg;                               // RS x 1536 bf16
  float* x1s  = (float*)Breg;                             // RS x 512 f32
  u16*  hidden= (u16*)(Breg + (size_t)RS * 2048);         // RS x 2048 bf16

  transpose_wb<<<dim3(1536/32, 512/32), 256, 0, stream>>>(qkv_w, wtq, 512, 1536);
  transpose_wb<<<dim3(512/32, 512/32), 256, 0, stream>>>(proj_w, wtp, 512, 512);
  transpose_wb<<<dim3(2048/32, 512/32), 256, 0, stream>>>(fc1_w, wtf1, 512, 2048);
  transpose_wb<<<dim3(512/32, 2048/32), 256, 0, stream>>>(fc2_w, wtf2, 2048, 512);
  build_tbl<<<2401, 256, 0, stream>>>(rpbt, tbl);

  for (int s = 0; s < NS; s++){
    ln1_gather<<<RS/4, 256, 0, stream>>>(x, n1s, n1b, Cs, s * RS);
    gemm_k<0, 512><<<(RS/128) * 12, 256, 0, stream>>>(Cs, wtq, qkv_b, qs, nullptr,
                                                      nullptr, nullptr, 12, 0);
    attn_k<<<(RS/49) * 16, 64, 0, stream>>>(qs, tbl, Cs);
    gemm_k<1, 512><<<(RS/128) * 4, 256, 0, stream>>>(Cs, wtp, proj_b, nullptr, x1s,
                                                     x, nullptr, 4, s * RS);
    ln2_k<<<RS/4, 256, 0, stream>>>(x1s, n2s, n2b, Cs);
    gemm_k<2, 512><<<(RS/128) * 16, 256, 0, stream>>>(Cs, wtf1, fc1_b, hidden, nullptr,
                                                      nullptr, nullptr, 16, 0);
    gemm_k<3, 2048><<<(RS/128) * 4, 256, 0, stream>>>(hidden, wtf2, fc2_b, nullptr, out,
                                                      nullptr, x1s, 4, s * RS);
  }
}

// Round 7
// 861.774 us; speedup vs baseline: 2.2747x; 1.0291x over previous
//
#include <hip/hip_runtime.h>
#include <cstdint>

typedef unsigned short u16;
typedef unsigned int   u32;
typedef unsigned long long u64;

typedef __bf16 bf16x8 __attribute__((ext_vector_type(8)));
typedef float  f32x4  __attribute__((ext_vector_type(4)));

union U16F { uint4 u; bf16x8 f; };

__device__ __forceinline__ u16 f2bf(float f){
  union { float f; u32 i; } x; x.f = f;
  u32 u = x.i;
  u += 0x7fffu + ((u >> 16) & 1u);   // round-to-nearest-even
  return (u16)(u >> 16);
}
__device__ __forceinline__ float b2f(u16 v){
  union { u32 i; float f; } x; x.i = ((u32)v) << 16; return x.f;
}

// XCD-aware chunked swizzle (T1): consecutive blockIdx round-robin across the
// 8 XCD L2s; remap so each XCD owns a CONTIGUOUS chunk of tile space, making
// blocks that share an operand slab co-resident on one L2. Requires nwg%8==0
// (all grids here are multiples of 8).
__device__ __forceinline__ int xcd_swz(int bid, int nwg){
  int cpx = nwg >> 3;
  return (bid & 7) * cpx + (bid >> 3);
}

// async global->LDS DMA, 16B per lane. LDS dest is wave-uniform base + lane*16;
// global src is per-lane. (guide §5: compiler never auto-emits this.)
typedef __attribute__((address_space(1))) const u32 GAS_u32;
typedef __attribute__((address_space(3))) u32 LAS_u32;
__device__ __forceinline__ void gll16(const u16* g, u16* l){
  __builtin_amdgcn_global_load_lds((GAS_u32*)g, (LAS_u32*)l, 16, 0, 0);
}

// window-order row -> (window bw, token t) and pixel under the +3 shift map
__device__ __forceinline__ void rowmap(int row, int& gpix, int& bw_o, int& t_o){
  int bw = (int)(((u64)row * 85599ull) >> 22);   // /49, exact for row<89240
  int t  = row - bw * 49;
  int b = bw >> 4, w = bw & 15;
  int wh = w >> 2, ww = w & 3;
  int i = (t * 37) >> 8, j = t - i * 7;          // /7, exact for t<86
  int y = wh * 7 + i + 3; if (y >= 28) y -= 28;
  int x = ww * 7 + j + 3; if (x >= 28) x -= 28;
  gpix = b * 784 + y * 28 + x;
  bw_o = bw; t_o = t;
}

// ---------- weight transpose + f32->bf16: in f32 (R x C) -> out bf16 (C x R) --
__global__ __launch_bounds__(256) void transpose_wb(const float* __restrict__ in,
                                                    u16* __restrict__ out,
                                                    int R, int C){
  __shared__ float t[32][33];
  int c0 = blockIdx.x * 32, r0 = blockIdx.y * 32;
  int tx = threadIdx.x & 31, ty = threadIdx.x >> 5;
#pragma unroll
  for (int i = ty; i < 32; i += 8) t[i][tx] = in[(long)(r0 + i) * C + c0 + tx];
  __syncthreads();
#pragma unroll
  for (int i = ty; i < 32; i += 8) out[(long)(c0 + i) * R + r0 + tx] = f2bf(t[tx][i]);
}

// ---------------- fused rel-pos-bias + shift-mask table (f32) ----------------
__global__ __launch_bounds__(256) void build_tbl(const float* __restrict__ rpbt,
                                                 float* __restrict__ tbl){
  int idx = blockIdx.x * 256 + threadIdx.x;
  if (idx >= 16 * 16 * 2401) return;
  int wh16 = idx / 2401; int ij = idx - wh16 * 2401;
  int w = wh16 >> 4, h = wh16 & 15;
  int i = ij / 49, j = ij - i * 49;
  int yi = i / 7, xi = i - yi * 7;
  int yj = j / 7, xj = j - yj * 7;
  int whh = w >> 2, www = w & 3;
  int ri = ((whh == 3 && yi >= 4) ? 2 : 0) + ((www == 3 && xi >= 4) ? 1 : 0);
  int rj = ((whh == 3 && yj >= 4) ? 2 : 0) + ((www == 3 && xj >= 4) ? 1 : 0);
  float mask = (ri == rj) ? 0.f : -100.f;
  int rel = (yi - yj + 6) * 13 + (xi - xj + 6);
  tbl[idx] = rpbt[rel * 16 + h] + mask;
}

// -------- LayerNorm1 (f32 in) with shift/window gather, bf16 out (slice) -----
__global__ __launch_bounds__(256) void ln1_gather(const float* __restrict__ x,
                                                  const float* __restrict__ sc,
                                                  const float* __restrict__ bi,
                                                  u16* __restrict__ hwin, int row0){
  int rloc = blockIdx.x * 4 + (threadIdx.x >> 6);
  int lane = threadIdx.x & 63;
  int gpix, bw, t; rowmap(row0 + rloc, gpix, bw, t);
  const float* src = x + (long)gpix * 512 + lane * 8;
  float4 a = *(const float4*)src;
  float4 b = *(const float4*)(src + 4);
  float v[8] = {a.x, a.y, a.z, a.w, b.x, b.y, b.z, b.w};
  float s = 0.f, s2 = 0.f;
#pragma unroll
  for (int k = 0; k < 8; k++){ s += v[k]; s2 += v[k] * v[k]; }
#pragma unroll
  for (int m = 1; m < 64; m <<= 1){ s += __shfl_xor(s, m); s2 += __shfl_xor(s2, m); }
  float mu = s * (1.f / 512.f);
  float var = s2 * (1.f / 512.f) - mu * mu;
  float rstd = rsqrtf(var + 1e-5f);
  float4 sa = *(const float4*)(sc + lane * 8);
  float4 sb = *(const float4*)(sc + lane * 8 + 4);
  float4 ba = *(const float4*)(bi + lane * 8);
  float4 bb = *(const float4*)(bi + lane * 8 + 4);
  float svec[8] = {sa.x, sa.y, sa.z, sa.w, sb.x, sb.y, sb.z, sb.w};
  float bvec[8] = {ba.x, ba.y, ba.z, ba.w, bb.x, bb.y, bb.z, bb.w};
  u32 o[4];
#pragma unroll
  for (int k = 0; k < 4; k++){
    float a0 = (v[2*k]   - mu) * rstd * svec[2*k]   + bvec[2*k];
    float a1 = (v[2*k+1] - mu) * rstd * svec[2*k+1] + bvec[2*k+1];
    o[k] = (u32)f2bf(a0) | ((u32)f2bf(a1) << 16);
  }
  uint4 ov = {o[0], o[1], o[2], o[3]};
  *(uint4*)(hwin + (long)rloc * 512 + lane * 8) = ov;
}

// ------------- LayerNorm2: slice-local f32 in, slice-local bf16 out ---------
__global__ __launch_bounds__(256) void ln2_k(const float* __restrict__ x1,
                                             const float* __restrict__ sc,
                                             const float* __restrict__ bi,
                                             u16* __restrict__ h2){
  int row = blockIdx.x * 4 + (threadIdx.x >> 6);
  int lane = threadIdx.x & 63;
  const float* src = x1 + (long)row * 512 + lane * 8;
  float4 a = *(const float4*)(src);
  float4 b = *(const float4*)(src + 4);
  float v[8] = {a.x, a.y, a.z, a.w, b.x, b.y, b.z, b.w};
  float s = 0.f, s2 = 0.f;
#pragma unroll
  for (int k = 0; k < 8; k++){ s += v[k]; s2 += v[k] * v[k]; }
#pragma unroll
  for (int m = 1; m < 64; m <<= 1){ s += __shfl_xor(s, m); s2 += __shfl_xor(s2, m); }
  float mu = s * (1.f / 512.f);
  float var = s2 * (1.f / 512.f) - mu * mu;
  float rstd = rsqrtf(var + 1e-5f);
  float4 sa = *(const float4*)(sc + lane * 8);
  float4 sb = *(const float4*)(sc + lane * 8 + 4);
  float4 ba = *(const float4*)(bi + lane * 8);
  float4 bb = *(const float4*)(bi + lane * 8 + 4);
  float svec[8] = {sa.x, sa.y, sa.z, sa.w, sb.x, sb.y, sb.z, sb.w};
  float bvec[8] = {ba.x, ba.y, ba.z, ba.w, bb.x, bb.y, bb.z, bb.w};
  u32 o[4];
#pragma unroll
  for (int k = 0; k < 4; k++){
    float a0 = (v[2*k]   - mu) * rstd * svec[2*k]   + bvec[2*k];
    float a1 = (v[2*k+1] - mu) * rstd * svec[2*k+1] + bvec[2*k+1];
    o[k] = (u32)f2bf(a0) | ((u32)f2bf(a1) << 16);
  }
  uint4 ov = {o[0], o[1], o[2], o[3]};
  *(uint4*)(h2 + (long)row * 512 + lane * 8) = ov;
}

// ------- 128x128 bf16 GEMM, global_load_lds direct staging (round-1 form) ----
// K-loop: issue 4x global_load_lds_dwordx4 -> barrier (vmcnt(0) drain) ->
// ds_read frags -> 16x MFMA -> barrier. + T1 XCD swizzle on blockIdx so the
// ntn blocks sharing an A-slab run on ONE XCD L2 (cuts A re-fetch).
// MODE 0: qkv  -> qs slice-local (row,1536) bf16, Q cols pre-scaled
// MODE 1: proj -> x1s(f32, slice-local) = out + gather(x f32 at global row)
// MODE 2: fc1  -> hidden(slice-local bf16) = gelu(out) = v*sigmoid(2z)
// MODE 3: fc2  -> d_out(f32) = out + x1s(local), scattered to pixel order
template<int MODE, int KDIM>
__global__ __launch_bounds__(256) void gemm_k(
    const u16* __restrict__ A, const u16* __restrict__ Bt,
    const float* __restrict__ bias,
    u16* __restrict__ o1, float* __restrict__ of,
    const float* __restrict__ xg, const float* __restrict__ x1r,
    int ntn, int erow0)
{
  __shared__ u16 Alds[128 * 32];
  __shared__ u16 Blds[128 * 32];
  const int tid = threadIdx.x;
  const int wave = tid >> 6, lane = tid & 63;
  const int quad = lane >> 4, l15 = lane & 15;
  const int bid = xcd_swz(blockIdx.x, gridDim.x);
  const int tn = bid % ntn, tm = bid / ntn;
  const int wy = wave >> 1, wx = wave & 1;

  // staging: lane l of wave w covers LDS rows {w*16 + (l>>2), +64}, 8-elem chunk (l&3)
  const u16* agp = A  + (size_t)(tm * 128 + wave * 16 + (lane >> 2)) * KDIM + (lane & 3) * 8;
  const u16* bgp = Bt + (size_t)(tn * 128 + wave * 16 + (lane >> 2)) * KDIM + (lane & 3) * 8;
  u16* alb = &Alds[wave * 512];   // + lane*16B implicit in the DMA
  u16* blb = &Blds[wave * 512];

  f32x4 acc[4][4];
#pragma unroll
  for (int i = 0; i < 4; i++)
#pragma unroll
    for (int j = 0; j < 4; j++) acc[i][j] = (f32x4){0.f, 0.f, 0.f, 0.f};

  for (int kt = 0; kt < KDIM / 32; ++kt){
    const u16* a0 = agp + kt * 32;
    const u16* b0 = bgp + kt * 32;
    gll16(a0, alb);
    gll16(a0 + (size_t)64 * KDIM, alb + 2048);
    gll16(b0, blb);
    gll16(b0 + (size_t)64 * KDIM, blb + 2048);
    __syncthreads();                       // vmcnt(0): DMA landed, all waves here
    U16F af[4], bf[4];
#pragma unroll
    for (int mi = 0; mi < 4; mi++)
      af[mi].u = *(const uint4*)&Alds[(wy * 64 + mi * 16 + l15) * 32 + quad * 8];
#pragma unroll
    for (int ni = 0; ni < 4; ni++)
      bf[ni].u = *(const uint4*)&Blds[(wx * 64 + ni * 16 + l15) * 32 + quad * 8];
#pragma unroll
    for (int mi = 0; mi < 4; mi++)
#pragma unroll
      for (int ni = 0; ni < 4; ni++)
        acc[mi][ni] = __builtin_amdgcn_mfma_f32_16x16x32_bf16(af[mi].f, bf[ni].f, acc[mi][ni], 0, 0, 0);
    __syncthreads();                       // protect LDS from next iter's DMA
  }

  // ---- epilogue ----
  const int colbase = tn * 128 + wx * 64;
  float bv[4];
#pragma unroll
  for (int ni = 0; ni < 4; ni++) bv[ni] = bias[colbase + ni * 16 + l15];
  const int rowbase = tm * 128 + wy * 64;

#pragma unroll
  for (int mi = 0; mi < 4; mi++){
#pragma unroll
    for (int r = 0; r < 4; r++){
      int rloc = rowbase + mi * 16 + quad * 4 + r;   // slice-local row
      int row = erow0 + rloc;                        // global window-order row
      if constexpr (MODE == 0){
        long obase = (long)rloc * 1536;
#pragma unroll
        for (int ni = 0; ni < 4; ni++){
          int col = colbase + ni * 16 + l15;
          float v = acc[mi][ni][r] + bv[ni];
          if (col < 512) v *= 0.17677669529663689f;   // q scale = 1/sqrt(32)
          o1[obase + col] = f2bf(v);
        }
      } else if constexpr (MODE == 1){
        int gpix, bw, t; rowmap(row, gpix, bw, t);
        long gbase = (long)gpix * 512;
        long obase = (long)rloc * 512;
#pragma unroll
        for (int ni = 0; ni < 4; ni++){
          int col = colbase + ni * 16 + l15;
          of[obase + col] = acc[mi][ni][r] + bv[ni] + xg[gbase + col];
        }
      } else if constexpr (MODE == 2){
        long obase = (long)rloc * 2048;
#pragma unroll
        for (int ni = 0; ni < 4; ni++){
          int col = colbase + ni * 16 + l15;
          float v = acc[mi][ni][r] + bv[ni];
          // gelu_tanh(v) == v*sigmoid(2z), 2z = v*(1.5957691 + 0.07135481 v^2)
          float zz = v * (1.5957691216f + 0.0713548135f * v * v);
          float sg = 1.f / (1.f + __expf(-zz));
          o1[obase + col] = f2bf(v * sg);
        }
      } else {
        int gpix, bw, t; rowmap(row, gpix, bw, t);
        long gbase = (long)gpix * 512;
        long rbase = (long)rloc * 512;
#pragma unroll
        for (int ni = 0; ni < 4; ni++){
          int col = colbase + ni * 16 + l15;
          of[gbase + col] = acc[mi][ni][r] + bv[ni] + x1r[rbase + col];
        }
      }
    }
  }
}

// ---------------- windowed attention: one wave per (window, head) ----------
// qkv slice-local (row,1536) bf16; writes slice-local aout rows (bw*49+t).
// XCD swizzle: the 16 heads of a window (sharing its 147KB qkv slab) run on
// one XCD L2.
__global__ __launch_bounds__(64) void attn_k(const u16* __restrict__ qkv,
                                             const float* __restrict__ tbl,
                                             u16* __restrict__ aout){
  __shared__ u16 P[64 * 72];
  __shared__ u16 Vt[32 * 72];
  const int blk = xcd_swz(blockIdx.x, gridDim.x);   // bw_local*16 + h
  const int bw = blk >> 4, h = blk & 15;
  const int lane = threadIdx.x & 63;
  const int quad = lane >> 4, l15 = lane & 15;
  const long rb = (long)(bw * 49) * 1536;
  const int hoff = h * 32;

  uint4 vraw[4];
#pragma unroll
  for (int p = 0; p < 4; p++){
    int t = p * 16 + (lane >> 2);
    int d0 = (lane & 3) * 8;
    vraw[p] = *(const uint4*)(qkv + rb + (long)t * 1536 + 1024 + hoff + d0);
  }

  U16F qf[4], kf[4];
#pragma unroll
  for (int mi = 0; mi < 4; mi++)
    qf[mi].u = *(const uint4*)(qkv + rb + (long)(mi * 16 + l15) * 1536 + hoff + quad * 8);
#pragma unroll
  for (int ni = 0; ni < 4; ni++)
    kf[ni].u = *(const uint4*)(qkv + rb + (long)(ni * 16 + l15) * 1536 + 512 + hoff + quad * 8);
  f32x4 S[4][4];
#pragma unroll
  for (int i = 0; i < 4; i++)
#pragma unroll
    for (int j = 0; j < 4; j++) S[i][j] = (f32x4){0.f, 0.f, 0.f, 0.f};
#pragma unroll
  for (int mi = 0; mi < 4; mi++)
#pragma unroll
    for (int ni = 0; ni < 4; ni++)
      S[mi][ni] = __builtin_amdgcn_mfma_f32_16x16x32_bf16(qf[mi].f, kf[ni].f, S[mi][ni], 0, 0, 0);

#pragma unroll
  for (int p = 0; p < 4; p++){
    int t = p * 16 + (lane >> 2);
    int d0 = (lane & 3) * 8;
    u32 wv[4] = {vraw[p].x, vraw[p].y, vraw[p].z, vraw[p].w};
#pragma unroll
    for (int k = 0; k < 4; k++){
      Vt[(d0 + 2 * k)     * 72 + t] = (u16)(wv[k] & 0xffff);
      Vt[(d0 + 2 * k + 1) * 72 + t] = (u16)(wv[k] >> 16);
    }
  }

  const int w = bw & 15;   // windows/slice multiple of 16: local == global mod 16
  const float* t0 = tbl + (long)(w * 16 + h) * 2401;
#pragma unroll
  for (int mi = 0; mi < 4; mi++){
#pragma unroll
    for (int r = 0; r < 4; r++){
      int row = mi * 16 + quad * 4 + r;
      float sv[4];
#pragma unroll
      for (int ni = 0; ni < 4; ni++){
        int col = ni * 16 + l15;
        float s;
        if (col < 49){
          s = S[mi][ni][r];
          if (row < 49) s += t0[row * 49 + col];
        } else s = -1e30f;
        sv[ni] = s;
      }
      float mx = fmaxf(fmaxf(sv[0], sv[1]), fmaxf(sv[2], sv[3]));
#pragma unroll
      for (int m = 1; m < 16; m <<= 1) mx = fmaxf(mx, __shfl_xor(mx, m));
      float e[4], sum = 0.f;
#pragma unroll
      for (int ni = 0; ni < 4; ni++){ e[ni] = __expf(sv[ni] - mx); sum += e[ni]; }
#pragma unroll
      for (int m = 1; m < 16; m <<= 1) sum += __shfl_xor(sum, m);
      float inv = 1.f / sum;
#pragma unroll
      for (int ni = 0; ni < 4; ni++)
        P[row * 72 + ni * 16 + l15] = f2bf(e[ni] * inv);
    }
  }
  __syncthreads();

  U16F vf[2][2];
#pragma unroll
  for (int ks = 0; ks < 2; ks++)
#pragma unroll
    for (int nj = 0; nj < 2; nj++)
      vf[ks][nj].u = *(const uint4*)&Vt[(nj * 16 + l15) * 72 + ks * 32 + quad * 8];
  f32x4 O[4][2];
#pragma unroll
  for (int i = 0; i < 4; i++)
#pragma unroll
    for (int j = 0; j < 2; j++) O[i][j] = (f32x4){0.f, 0.f, 0.f, 0.f};
#pragma unroll
  for (int ks = 0; ks < 2; ks++){
#pragma unroll
    for (int mi = 0; mi < 4; mi++){
      U16F pf;
      pf.u = *(const uint4*)&P[(mi * 16 + l15) * 72 + ks * 32 + quad * 8];
#pragma unroll
      for (int nj = 0; nj < 2; nj++)
        O[mi][nj] = __builtin_amdgcn_mfma_f32_16x16x32_bf16(pf.f, vf[ks][nj].f, O[mi][nj], 0, 0, 0);
    }
  }
#pragma unroll
  for (int mi = 0; mi < 4; mi++){
#pragma unroll
    for (int r = 0; r < 4; r++){
      int t = mi * 16 + quad * 4 + r;
      if (t < 49){
        long ob = ((long)(bw * 49 + t)) * 512 + hoff;
#pragma unroll
        for (int nj = 0; nj < 2; nj++)
          aout[ob + nj * 16 + l15] = f2bf(O[mi][nj][r]);
      }
    }
  }
}

// ---------------- launch ----------------
extern "C" void kernel_launch(void* const* d_in, const int* in_sizes, int n_in,
                              void* d_out, int out_size, void* d_ws, size_t ws_size,
                              hipStream_t stream)
{
  (void)in_sizes; (void)n_in; (void)out_size;
  const float* x      = (const float*)d_in[0];
  const float* qkv_w  = (const float*)d_in[1];
  const float* qkv_b  = (const float*)d_in[2];
  const float* proj_w = (const float*)d_in[3];
  const float* proj_b = (const float*)d_in[4];
  const float* rpbt   = (const float*)d_in[5];
  const float* n1s    = (const float*)d_in[6];
  const float* n1b    = (const float*)d_in[7];
  const float* n2s    = (const float*)d_in[8];
  const float* n2b    = (const float*)d_in[9];
  const float* fc1_w  = (const float*)d_in[10];
  const float* fc1_b  = (const float*)d_in[11];
  const float* fc2_w  = (const float*)d_in[12];
  const float* fc2_b  = (const float*)d_in[13];
  float* out = (float*)d_out;

  // ---- workspace plan: NS slices; prefer NS=1 (one big grid per GEMM class,
  // 392-block tails become 1568-block grids), fall back if ws too small ----
  const size_t FIXED = ((size_t)614656 * 4 + 256) + ((size_t)1536 * 512 * 2 + 256) +
                       ((size_t)512 * 512 * 2 + 256) + ((size_t)2048 * 512 * 2 + 256) +
                       ((size_t)512 * 2048 * 2 + 256);
  int NS = 1;
  for (; NS <= 4; NS *= 2){
    size_t rs = 50176 / NS;
    size_t need = FIXED + (rs * 1024 + 256) + rs * 6144 + 1024;
    if (need <= ws_size) break;
  }
  if (NS > 4) NS = 4;
  const int RS = 50176 / NS;        // rows per slice (multiple of 128 and 784)

  char* ws = (char*)d_ws;
  size_t off = 0;
  auto alloc = [&](size_t bytes) -> char* {
    char* p = ws + off;
    off = (off + bytes + 255) & ~(size_t)255;
    return p;
  };
  float* tbl  = (float*)alloc((size_t)614656 * 4);
  u16*  wtq   = (u16*)alloc((size_t)1536 * 512 * 2);
  u16*  wtp   = (u16*)alloc((size_t)512 * 512 * 2);
  u16*  wtf1  = (u16*)alloc((size_t)2048 * 512 * 2);
  u16*  wtf2  = (u16*)alloc((size_t)512 * 2048 * 2);
  u16*  Cs    = (u16*)alloc((size_t)RS * 512 * 2);        // ln1 -> attnout -> h2
  char* Breg  = alloc((size_t)RS * 6144);                 // qs | x1s+hidden
  u16*  qs    = (u16*)Breg;                               // RS x 1536 bf16
  float* x1s  = (float*)Breg;                             // RS x 512 f32
  u16*  hidden= (u16*)(Breg + (size_t)RS * 2048);         // RS x 2048 bf16

  transpose_wb<<<dim3(1536/32, 512/32), 256, 0, stream>>>(qkv_w, wtq, 512, 1536);
  transpose_wb<<<dim3(512/32, 512/32), 256, 0, stream>>>(proj_w, wtp, 512, 512);
  transpose_wb<<<dim3(2048/32, 512/32), 256, 0, stream>>>(fc1_w, wtf1, 512, 2048);
  transpose_wb<<<dim3(512/32, 2048/32), 256, 0, stream>>>(fc2_w, wtf2, 2048, 512);
  build_tbl<<<2401, 256, 0, stream>>>(rpbt, tbl);

  for (int s = 0; s < NS; s++){
    ln1_gather<<<RS/4, 256, 0, stream>>>(x, n1s, n1b, Cs, s * RS);
    gemm_k<0, 512><<<(RS/128) * 12, 256, 0, stream>>>(Cs, wtq, qkv_b, qs, nullptr,
                                                      nullptr, nullptr, 12, 0);
    attn_k<<<(RS/49) * 16, 64, 0, stream>>>(qs, tbl, Cs);
    gemm_k<1, 512><<<(RS/128) * 4, 256, 0, stream>>>(Cs, wtp, proj_b, nullptr, x1s,
                                                     x, nullptr, 4, s * RS);
    ln2_k<<<RS/4, 256, 0, stream>>>(x1s, n2s, n2b, Cs);
    gemm_k<2, 512><<<(RS/128) * 16, 256, 0, stream>>>(Cs, wtf1, fc1_b, hidden, nullptr,
                                                      nullptr, nullptr, 16, 0);
    gemm_k<3, 2048><<<(RS/128) * 4, 256, 0, stream>>>(hidden, wtf2, fc2_b, nullptr, out,
                                                      nullptr, x1s, 4, s * RS);
  }
}